// Round 19
// baseline (367.953 us; speedup 1.0000x reference)
//
#include <hip/hip_runtime.h>
#include <math.h>

// Problem constants (match reference setup_inputs)
constexpr int B = 2;
constexpr int N = 4096;
constexpr int C = 32;
constexpr int D = 256;
constexpr int K = 16;
constexpr int NW = N / 32;   // adjacency bitmask words per row = 128
constexpr int CAP = 128;     // max neighbors per row (16 out + in-degree)
constexpr int ROWS = B * N;  // 8192

__device__ __forceinline__ unsigned short f2bf(float f) {   // RNE f32 -> bf16
    unsigned u = __float_as_uint(f);
    return (unsigned short)((u + 0x7fffu + ((u >> 16) & 1u)) >> 16);
}
__device__ __forceinline__ float bflo(unsigned u) { return __uint_as_float(u << 16); }
__device__ __forceinline__ float bfhi(unsigned u) { return __uint_as_float(u & 0xffff0000u); }

// ---------------------------------------------------------------------------
// Kernel 1: per-row preprocess: centers(+sqnorm or INF if invalid), a
// PRE-NORMALIZED bf16 copy of the feature row, and mu0[r] = softmax moments
// of the row's raw logits. Also zeroes the adjacency bitmask and the
// per-row version flags used by the dataflow iteration kernel.
__global__ void pre_kernel(const float* __restrict__ rois,
                           const float* __restrict__ feats,
                           const float* __restrict__ logits,
                           float4* __restrict__ centers4,
                           unsigned short* __restrict__ fnbf,
                           float2* __restrict__ mu0,
                           uint2* __restrict__ adj_zero,
                           unsigned* __restrict__ ver) {
    const int t = threadIdx.x;
    const int wid = t >> 6, lane = t & 63;
    const int r = blockIdx.x * 4 + wid;

    // zero adjacency: 2048 blocks * 256 threads == ROWS*NW/2 uint2 elements
    adj_zero[blockIdx.x * 256 + t] = make_uint2(0u, 0u);
    // zero version flags (8192 words, first 32 blocks)
    if (blockIdx.x < 32) ver[blockIdx.x * 256 + t] = 0u;

    if (r >= ROWS) return;

    const float4* f4 = reinterpret_cast<const float4*>(feats) + (size_t)r * (D / 4);
    float4 v = f4[lane];
    float ss = v.x * v.x + v.y * v.y + v.z * v.z + v.w * v.w;
#pragma unroll
    for (int off = 32; off; off >>= 1) ss += __shfl_xor(ss, off);

    const float invn = 1.0f / fmaxf(sqrtf(ss), 1e-6f);
    unsigned u0 = (unsigned)f2bf(v.x * invn) | ((unsigned)f2bf(v.y * invn) << 16);
    unsigned u1 = (unsigned)f2bf(v.z * invn) | ((unsigned)f2bf(v.w * invn) << 16);
    *reinterpret_cast<uint2*>(fnbf + (size_t)r * D + lane * 4) = make_uint2(u0, u1);

    // softmax moments of own logits (lanes 0..31)
    if (lane < C) {
        float x = logits[(size_t)r * C + lane];
        float mx = x;
#pragma unroll
        for (int off = 16; off; off >>= 1) mx = fmaxf(mx, __shfl_xor(mx, off, 32));
        float e = expf(x - mx);
        const float fc = (float)lane;
        float s0 = e, s1 = e * fc, s2 = e * fc * fc;
#pragma unroll
        for (int off = 16; off; off >>= 1) {
            s0 += __shfl_xor(s0, off, 32);
            s1 += __shfl_xor(s1, off, 32);
            s2 += __shfl_xor(s2, off, 32);
        }
        if (lane == 0) mu0[r] = make_float2(s1 / s0, s2 / s0);
    }

    if (lane == 0) {
        const float* rp = rois + (size_t)r * 6;
        float a0 = rp[0], a1 = rp[1], a2 = rp[2], a3 = rp[3], a4 = rp[4], a5 = rp[5];
        float cx = (a0 + a3) * 0.5f, cy = (a1 + a4) * 0.5f, cz = (a2 + a5) * 0.5f;
        float sq = cx * cx + cy * cy + cz * cz;
        float s = fabsf(a0) + fabsf(a1) + fabsf(a2) + fabsf(a3) + fabsf(a4) + fabsf(a5);
        centers4[r] = make_float4(cx, cy, cz, (s > 0.0f) ? sq : INFINITY);
    }
}

// ---------------------------------------------------------------------------
// Kernel 2: exact 16-NN, chunk-in-register structure (see R8 notes).
__global__ __launch_bounds__(1024, 8) void knn_kernel(const float4* __restrict__ centers4,
                                                      unsigned* __restrict__ adj) {
    __shared__ float4 s_c[N];                        // 64 KB
    __shared__ unsigned s_pm[16][64];                // 4 KB subset-min bits
    __shared__ unsigned long long s_buf[16][64];     // 8 KB survivor keys
    __shared__ int s_cnt[16];
    __shared__ float s_tau[16];

    const int t = threadIdx.x;
    const int lane = t & 63;
    const int wv = t >> 6;
    const int r0 = blockIdx.x * 16;        // first global row of block
    const int nbase = r0 & (N - 1);        // first in-batch row index
    const int gbase = r0 - nbase;          // batch offset (0 or N)

    if (t < 16) s_cnt[t] = 0;
    ((unsigned*)s_pm)[t] = 0x7F800000u;    // +INF bits (1024 entries exactly)
    for (int i = t; i < N; i += 1024) s_c[i] = centers4[gbase + i];
    __syncthreads();

    // wave-owned candidate chunk, kept in registers
    float4 cmv[4];
    int    mv[4];
#pragma unroll
    for (int u = 0; u < 4; ++u) {
        mv[u] = (wv << 8) + (u << 6) + lane;
        cmv[u] = s_c[mv[u]];
    }

    // ---- pass 1: per-row min over this lane's 4 candidates; merge via atomicMin ----
#pragma unroll 4
    for (int rr = 0; rr < 16; ++rr) {
        const int nrow = nbase + rr;
        const float4 rc = s_c[nrow];       // same-address broadcast, conflict-free
        float mn = INFINITY;
#pragma unroll
        for (int u = 0; u < 4; ++u) {
            float dist = fmaxf(rc.w + cmv[u].w -
                               2.0f * (rc.x * cmv[u].x + rc.y * cmv[u].y + rc.z * cmv[u].z), 0.0f);
            mn = fminf(mn, (mv[u] == nrow) ? INFINITY : dist);
        }
        atomicMin(&s_pm[rr][lane], __float_as_uint(mn));
    }
    __syncthreads();

    // ---- tau per row: wave rr sorts its row's 64 subset minima ----
    {
        float v = __uint_as_float(s_pm[wv][lane]);
#pragma unroll
        for (int k = 2; k <= 64; k <<= 1) {
#pragma unroll
            for (int j = k >> 1; j > 0; j >>= 1) {
                float o = __shfl_xor(v, j);
                bool take_min = (((lane & j) == 0) == ((lane & k) == 0));
                v = take_min ? fminf(v, o) : fmaxf(v, o);
            }
        }
        if (lane == 15) s_tau[wv] = v;     // 16th smallest
    }
    __syncthreads();

    // ---- pass 2: append survivors from the register chunk for all 16 rows ----
#pragma unroll 4
    for (int rr = 0; rr < 16; ++rr) {
        const int nrow = nbase + rr;
        const float tau = s_tau[rr];
        const float4 rc = s_c[nrow];
#pragma unroll
        for (int u = 0; u < 4; ++u) {
            float dist = fmaxf(rc.w + cmv[u].w -
                               2.0f * (rc.x * cmv[u].x + rc.y * cmv[u].y + rc.z * cmv[u].z), 0.0f);
            if (dist <= tau && mv[u] != nrow) {
                int pos = atomicAdd(&s_cnt[rr], 1);
                if (pos < 64)
                    s_buf[rr][pos] = ((unsigned long long)__float_as_uint(dist) << 32)
                                     | (unsigned)mv[u];
            }
        }
    }
    __syncthreads();

    // ---- selection: wave rr owns row rr ----
    const int rg = r0 + wv;                // global row
    const int n = nbase + wv;              // in-batch row
    const int cnt = s_cnt[wv];

    int my_sel = -1;
    if (cnt <= 64) {
        unsigned long long key = (lane < cnt) ? s_buf[wv][lane] : ~0ull;
#pragma unroll
        for (int k = 2; k <= 64; k <<= 1) {
#pragma unroll
            for (int j = k >> 1; j > 0; j >>= 1) {
                unsigned long long o = __shfl_xor(key, j);
                bool take_min = (((lane & j) == 0) == ((lane & k) == 0));
                unsigned long long mn = (key < o) ? key : o;
                unsigned long long mx = (key < o) ? o : key;
                key = take_min ? mn : mx;
            }
        }
        if (lane < K && key != ~0ull) my_sel = (int)(unsigned)key;
    } else {
        // exact fallback: 16 rounds of full rescan-argmin over LDS table
        const float4 cq = s_c[n];
        unsigned long long removed = 0ull;
        for (int round = 0; round < K; ++round) {
            float bd = INFINITY; int bi = 0x7FFFFFFF;
            for (int j = 0; j < 64; ++j) {
                const int m = lane + (j << 6);
                float4 cm = s_c[m];
                float dist = fmaxf(cq.w + cm.w -
                                   2.0f * (cq.x * cm.x + cq.y * cm.y + cq.z * cm.z), 0.0f);
                bool skip = ((removed >> j) & 1ull) || (m == n);
                if (!skip && dist < bd) { bd = dist; bi = m; }
            }
            float md = bd;
#pragma unroll
            for (int off = 32; off; off >>= 1) md = fminf(md, __shfl_xor(md, off));
            if (md == INFINITY) break;
            int kk = (bd == md) ? bi : 0x7FFFFFFF;
#pragma unroll
            for (int off = 32; off; off >>= 1) kk = min(kk, __shfl_xor(kk, off));
            if (lane == round) my_sel = kk;
            if (kk == bi) removed |= 1ull << (bi >> 6);
        }
    }

    if (my_sel >= 0) {
        atomicOr(&adj[(size_t)rg * NW + (my_sel >> 5)], 1u << (my_sel & 31));
        atomicOr(&adj[(size_t)(gbase + my_sel) * NW + (n >> 5)], 1u << (n & 31));
    }
}

// ---------------------------------------------------------------------------
// Kernel 3: build weighted neighbor lists — barrier-free, one wave per row
// (R13 structure) + it1 fused cheaply via precomputed mu0 broadcast (R18).
__global__ __launch_bounds__(256) void build_kernel(const unsigned short* __restrict__ fnbf,
                             const float4* __restrict__ centers4,
                             const unsigned* __restrict__ adj,
                             const float2* __restrict__ mu0,
                             uint2* __restrict__ nbr,
                             int* __restrict__ nbr_cnt,
                             const float* __restrict__ raw_sigma,
                             const float* __restrict__ logits,
                             const float* __restrict__ raw_smooth,
                             float2* __restrict__ mu1) {
    const int t = threadIdx.x;
    const int lane = t & 63;
    const int wv = t >> 6;          // 0..3
    const int r = blockIdx.x * 4 + wv;
    const int base = r - (r & (N - 1));

    __shared__ float4 s_q[4][16 * 5];   // per-wave padded Q: idx 5e+s (+1 pad/e)
    __shared__ int    s_list[4][CAP];
    __shared__ float  s_w[4][CAP];

    // ---- adjacency compaction (wave-local, ascending => deterministic) ----
    uint2 wpair = *reinterpret_cast<const uint2*>(adj + (size_t)r * NW + 2 * lane);
    const int pc = __popc(wpair.x) + __popc(wpair.y);
    int sc = pc;
#pragma unroll
    for (int off = 1; off < 64; off <<= 1) {
        int o = __shfl_up(sc, off);
        if (lane >= off) sc += o;
    }
    const int total = __shfl(sc, 63);
    const int cnt = total > CAP ? CAP : total;
    int o = sc - pc;                   // exclusive prefix
    {
        unsigned ww = wpair.x; int mb = lane * 64;
        while (ww) { int b = __ffs(ww) - 1; if (o < CAP) s_list[wv][o] = mb + b; ++o; ww &= ww - 1; }
        ww = wpair.y; mb = lane * 64 + 32;
        while (ww) { int b = __ffs(ww) - 1; if (o < CAP) s_list[wv][o] = mb + b; ++o; ww &= ww - 1; }
    }

    // ---- stage q row (bf16 -> f32) into padded per-wave layout ----
    {
        uint2 qw = *reinterpret_cast<const uint2*>(fnbf + (size_t)r * D + 4 * lane);
        float4 qv = make_float4(bflo(qw.x), bfhi(qw.x), bflo(qw.y), bfhi(qw.y));
        const int e = (lane & 31) >> 1;
        const int s = ((lane >> 5) << 1) | (lane & 1);
        s_q[wv][5 * e + s] = qv;
    }

    const float rs = raw_sigma[0];
    const float sigma = fmaxf(log1pf(expf(rs)), 1e-6f);
    const float nhalf_inv_s2 = -0.5f / (sigma * sigma);
    const float smooth = log1pf(expf(raw_smooth[0]));
    const float4 cq = centers4[r];
    const uint4* fn4 = reinterpret_cast<const uint4*>(fnbf);

    // it1 accumulators (group-redundant; /16 exact at the end)
    float am0 = 0.0f, am1 = 0.0f, am2 = 0.0f;

    // ---- gather: 16-lane groups, 4 neighbors per wave per step ----
    {
        const int g = lane >> 4;    // neighbor slot (0..3)
        const int e = lane & 15;    // element slice (0..15)
        for (int i0 = 0; i0 < cnt; i0 += 4) {
            const int i = i0 + g;
            const bool act = (i < cnt);
            const int gm = base + s_list[wv][act ? i : 0];
            uint4 a = fn4[(size_t)gm * 32 + e];        // elems [8e, 8e+8)
            uint4 b = fn4[(size_t)gm * 32 + 16 + e];   // elems [128+8e, 128+8e+8)
            float4 cm = centers4[gm];                  // broadcast within group
            float2 nmu = mu0[gm];                      // broadcast within group
            float4 qa0 = s_q[wv][5 * e + 0], qa1 = s_q[wv][5 * e + 1];
            float4 qb0 = s_q[wv][5 * e + 2], qb1 = s_q[wv][5 * e + 3];
            float p = bflo(a.x) * qa0.x + bfhi(a.x) * qa0.y
                    + bflo(a.y) * qa0.z + bfhi(a.y) * qa0.w
                    + bflo(a.z) * qa1.x + bfhi(a.z) * qa1.y
                    + bflo(a.w) * qa1.z + bfhi(a.w) * qa1.w
                    + bflo(b.x) * qb0.x + bfhi(b.x) * qb0.y
                    + bflo(b.y) * qb0.z + bfhi(b.y) * qb0.w
                    + bflo(b.z) * qb1.x + bfhi(b.z) * qb1.y
                    + bflo(b.w) * qb1.z + bfhi(b.w) * qb1.w;
#pragma unroll
            for (int off = 1; off < 16; off <<= 1) p += __shfl_xor(p, off);
            float aff = fminf(fmaxf((p + 1.0f) * 0.5f, 0.0f), 1.0f);
            float dist = fmaxf(cq.w + cm.w -
                               2.0f * (cq.x * cm.x + cq.y * cm.y + cq.z * cm.z), 0.0f);
            float w = expf(dist * nhalf_inv_s2) * aff;
            if (e == 0 && act) s_w[wv][i] = w;
            if (act) {
                am0 += w;
                am1 += w * nmu.x;
                am2 += w * nmu.y;
            }
        }
    }

    // ---- wave-local weight sum (deterministic) + normalize + write ----
    float ps = 0.0f;
    for (int i = lane; i < cnt; i += 64) ps += s_w[wv][i];
#pragma unroll
    for (int off = 32; off; off >>= 1) ps += __shfl_xor(ps, off);
    const float inv_sum = 1.0f / fmaxf(ps, 1e-6f);

    for (int i = lane; i < cnt; i += 64) {
        nbr[(size_t)r * CAP + i] = make_uint2((unsigned)s_list[wv][i],
                                              __float_as_uint(s_w[wv][i] * inv_sum));
    }
    if (lane == 0) nbr_cnt[r] = cnt;

    // ---- it1 for own row: reduce accumulators (/16 exact), refined, mu1 ----
#pragma unroll
    for (int off = 32; off; off >>= 1) {
        am0 += __shfl_xor(am0, off);
        am1 += __shfl_xor(am1, off);
        am2 += __shfl_xor(am2, off);
    }
    const float m0 = am0 * 0.0625f * inv_sum;
    const float m1 = am1 * 0.0625f * inv_sum;
    const float m2 = am2 * 0.0625f * inv_sum;

    if (lane < C) {
        const float fc = (float)lane;
        float pw = (m2 - 2.0f * fc * m1 + fc * fc * m0) * (1.0f / 961.0f);
        float refined = logits[(size_t)r * C + lane] - smooth * pw;
        float mx = refined;
#pragma unroll
        for (int off = 16; off; off >>= 1) mx = fmaxf(mx, __shfl_xor(mx, off, 32));
        float e = expf(refined - mx);
        float s0 = e, s1 = e * fc, s2 = e * fc * fc;
#pragma unroll
        for (int off = 16; off; off >>= 1) {
            s0 += __shfl_xor(s0, off, 32);
            s1 += __shfl_xor(s1, off, 32);
            s2 += __shfl_xor(s2, off, 32);
        }
        if (lane == 0) mu1[r] = make_float2(s1 / s0, s2 / s0);
    }
}

// ---------------------------------------------------------------------------
// Kernel 4: iterations 2..5 in ONE dispatch, dataflow-synchronized.
// Per-row publish: 8B mu via relaxed AGENT atomic store, then per-row
// version word via RELEASE AGENT store. Consumers spin with ACQUIRE loads
// (per-row flags -> ~30 readers/line, unlike R16's single hot counter) and
// read mu as relaxed AGENT 64-bit atomic loads (LLC-coherent across XCDs).
// Level-DAG + full co-residency (1024 blocks x 4 waves = 4096 of 8192 wave
// slots, no LDS) => no deadlock. ver[] zeroed by pre each call => replay-
// deterministic. FP order per iteration identical to R18's iter_kernel.
template<int PH, bool LAST>
__device__ __forceinline__ void mf_phase(int r, int c, int nj,
                                         const int* mIdx, const float* mW,
                                         float x, float smooth,
                                         const float2* mi, float2* mo,
                                         float* out, unsigned* ver) {
    float m0 = 0.0f, m1 = 0.0f, m2 = 0.0f;
#pragma unroll
    for (int u = 0; u < 4; ++u) {
        if (u < nj) {
            const int m = mIdx[u];
            if (PH > 0) {
                while (__hip_atomic_load(&ver[m], __ATOMIC_ACQUIRE,
                                         __HIP_MEMORY_SCOPE_AGENT) < (unsigned)PH)
                    __builtin_amdgcn_s_sleep(1);
            }
            unsigned long long pk = __hip_atomic_load(
                reinterpret_cast<const unsigned long long*>(mi + m),
                __ATOMIC_RELAXED, __HIP_MEMORY_SCOPE_AGENT);
            float mux = __uint_as_float((unsigned)pk);
            float muy = __uint_as_float((unsigned)(pk >> 32));
            float w = mW[u];
            m0 += w; m1 += w * mux; m2 += w * muy;
        }
    }
#pragma unroll
    for (int off = 16; off; off >>= 1) {
        m0 += __shfl_xor(m0, off, 32);
        m1 += __shfl_xor(m1, off, 32);
        m2 += __shfl_xor(m2, off, 32);
    }
    const float fc = (float)c;
    float pw = (m2 - 2.0f * fc * m1 + fc * fc * m0) * (1.0f / 961.0f);
    float refined = x - smooth * pw;

    if (LAST) {
        out[(size_t)r * C + c] = refined;
    } else {
        float mx = refined;
#pragma unroll
        for (int off = 16; off; off >>= 1) mx = fmaxf(mx, __shfl_xor(mx, off, 32));
        float e = expf(refined - mx);
        float s0 = e, s1 = e * fc, s2 = e * fc * fc;
#pragma unroll
        for (int off = 16; off; off >>= 1) {
            s0 += __shfl_xor(s0, off, 32);
            s1 += __shfl_xor(s1, off, 32);
            s2 += __shfl_xor(s2, off, 32);
        }
        if (c == 0) {
            unsigned long long pk =
                ((unsigned long long)__float_as_uint(s2 / s0) << 32) |
                (unsigned long long)__float_as_uint(s1 / s0);
            __hip_atomic_store(reinterpret_cast<unsigned long long*>(mo + r), pk,
                               __ATOMIC_RELAXED, __HIP_MEMORY_SCOPE_AGENT);
            __hip_atomic_store(ver + r, (unsigned)(PH + 1),
                               __ATOMIC_RELEASE, __HIP_MEMORY_SCOPE_AGENT);
        }
    }
}

__global__ __launch_bounds__(256) void iters_kernel(const float* __restrict__ logits,
                                                    const uint2* __restrict__ nbr,
                                                    const int* __restrict__ nbr_cnt,
                                                    const float2* __restrict__ mu1,
                                                    float2* __restrict__ mu2,
                                                    float2* __restrict__ mu3,
                                                    float2* __restrict__ mu4,
                                                    float* __restrict__ out,
                                                    const float* __restrict__ raw_smooth,
                                                    unsigned* __restrict__ ver) {
    const int t = threadIdx.x;
    const int r = blockIdx.x * 8 + (t >> 5);
    const int c = t & 31;
    const int base = r - (r & (N - 1));
    const float smooth = log1pf(expf(raw_smooth[0]));
    const int cnt = nbr_cnt[r];
    const uint2* np = nbr + (size_t)r * CAP;
    const float x = logits[(size_t)r * C + c];

    // register-cache this lane's (idx, w) pairs (cnt <= 128 = 4*32)
    int mIdx[4]; float mW[4]; int nj = 0;
#pragma unroll
    for (int u = 0; u < 4; ++u) {
        const int j = c + u * 32;
        if (j < cnt) {
            uint2 e = np[j];
            mIdx[u] = base + (int)e.x;
            mW[u] = __uint_as_float(e.y);
            nj = u + 1;
        } else {
            mIdx[u] = base; mW[u] = 0.0f;
        }
    }

    mf_phase<0, false>(r, c, nj, mIdx, mW, x, smooth, mu1, mu2, out, ver);  // it2
    mf_phase<1, false>(r, c, nj, mIdx, mW, x, smooth, mu2, mu3, out, ver);  // it3
    mf_phase<2, false>(r, c, nj, mIdx, mW, x, smooth, mu3, mu4, out, ver);  // it4
    mf_phase<3, true >(r, c, nj, mIdx, mW, x, smooth, mu4, mu4, out, ver);  // it5 -> out
}

// ---------------------------------------------------------------------------
extern "C" void kernel_launch(void* const* d_in, const int* in_sizes, int n_in,
                              void* d_out, int out_size, void* d_ws, size_t ws_size,
                              hipStream_t stream) {
    const float* logits     = (const float*)d_in[0];
    const float* rois       = (const float*)d_in[1];
    const float* feats      = (const float*)d_in[2];
    const float* raw_sigma  = (const float*)d_in[3];
    const float* raw_smooth = (const float*)d_in[4];
    float* out = (float*)d_out;

    char* ws = (char*)d_ws;
    size_t off = 0;
    auto alloc = [&](size_t bytes) -> void* {
        void* p = ws + off;
        off += (bytes + 255) & ~(size_t)255;
        return p;
    };
    float4*         centers4 = (float4*)        alloc((size_t)ROWS * sizeof(float4));
    unsigned short* fnbf     = (unsigned short*)alloc((size_t)ROWS * D * 2);
    unsigned*       adj      = (unsigned*)      alloc((size_t)ROWS * NW * 4);
    uint2*          nbr      = (uint2*)         alloc((size_t)ROWS * CAP * 8);
    int*            nbr_cnt  = (int*)           alloc((size_t)ROWS * 4);
    float2*         mu_0     = (float2*)        alloc((size_t)ROWS * 8);
    float2*         mu_1     = (float2*)        alloc((size_t)ROWS * 8);
    float2*         mu_2     = (float2*)        alloc((size_t)ROWS * 8);
    float2*         mu_3     = (float2*)        alloc((size_t)ROWS * 8);
    float2*         mu_4     = (float2*)        alloc((size_t)ROWS * 8);
    unsigned*       ver      = (unsigned*)      alloc((size_t)ROWS * 4);

    pre_kernel<<<ROWS / 4, 256, 0, stream>>>(rois, feats, logits, centers4, fnbf,
                                             mu_0, (uint2*)adj, ver);
    knn_kernel<<<ROWS / 16, 1024, 0, stream>>>(centers4, adj);
    // build + iteration 1 (cheap mu0-broadcast form) -> mu_1
    build_kernel<<<ROWS / 4, 256, 0, stream>>>(fnbf, centers4, adj, mu_0,
                                               nbr, nbr_cnt, raw_sigma, logits,
                                               raw_smooth, mu_1);
    // iterations 2..5 in one dataflow dispatch
    iters_kernel<<<ROWS / 8, 256, 0, stream>>>(logits, nbr, nbr_cnt,
                                               mu_1, mu_2, mu_3, mu_4,
                                               out, raw_smooth, ver);
}

// Round 20
// 74.516 us; speedup vs baseline: 4.9379x; 4.9379x over previous
//
#include <hip/hip_runtime.h>
#include <math.h>

// Problem constants (match reference setup_inputs)
constexpr int B = 2;
constexpr int N = 4096;
constexpr int C = 32;
constexpr int D = 256;
constexpr int K = 16;
constexpr int NW = N / 32;   // adjacency bitmask words per row = 128
constexpr int CAP = 128;     // max neighbors per row (16 out + in-degree)
constexpr int ROWS = B * N;  // 8192

__device__ __forceinline__ unsigned short f2bf(float f) {   // RNE f32 -> bf16
    unsigned u = __float_as_uint(f);
    return (unsigned short)((u + 0x7fffu + ((u >> 16) & 1u)) >> 16);
}
__device__ __forceinline__ float bflo(unsigned u) { return __uint_as_float(u << 16); }
__device__ __forceinline__ float bfhi(unsigned u) { return __uint_as_float(u & 0xffff0000u); }

// ---------------------------------------------------------------------------
// Kernel 1: exact 16-NN (R8 chunk-in-register structure) WITH pre_kernel's
// per-row work absorbed into the pre-barrier phase: wave wv owns row r0+wv
// and (a) normalizes its feature row to bf16 (fnbf), (b) computes mu0 =
// softmax moments of its logits, (c) writes centers4[rg] from rois. The
// LDS center table is computed directly from rois in the staging loop
// (~10 VALU/row, hidden under staging). Adjacency zeroing moved to a
// hipMemsetAsync before this kernel (other blocks' atomicOrs race with
// in-kernel zeroing, so it cannot be fused).
__global__ __launch_bounds__(1024, 8) void knn_kernel(const float* __restrict__ rois,
                                                      const float* __restrict__ feats,
                                                      const float* __restrict__ logits,
                                                      float4* __restrict__ centers4,
                                                      unsigned short* __restrict__ fnbf,
                                                      float2* __restrict__ mu0,
                                                      unsigned* __restrict__ adj) {
    __shared__ float4 s_c[N];                        // 64 KB
    __shared__ unsigned s_pm[16][64];                // 4 KB subset-min bits
    __shared__ unsigned long long s_buf[16][64];     // 8 KB survivor keys
    __shared__ int s_cnt[16];
    __shared__ float s_tau[16];

    const int t = threadIdx.x;
    const int lane = t & 63;
    const int wv = t >> 6;
    const int r0 = blockIdx.x * 16;        // first global row of block
    const int nbase = r0 & (N - 1);        // first in-batch row index
    const int gbase = r0 - nbase;          // batch offset (0 or N)
    const int rg0 = r0 + wv;               // this wave's own row

    if (t < 16) s_cnt[t] = 0;
    ((unsigned*)s_pm)[t] = 0x7F800000u;    // +INF bits (1024 entries exactly)

    // ---- absorbed pre-work for own row (one wave per row) ----
    {
        const float4* f4 = reinterpret_cast<const float4*>(feats) + (size_t)rg0 * (D / 4);
        float4 v = f4[lane];
        float ss = v.x * v.x + v.y * v.y + v.z * v.z + v.w * v.w;
#pragma unroll
        for (int off = 32; off; off >>= 1) ss += __shfl_xor(ss, off);
        const float invn = 1.0f / fmaxf(sqrtf(ss), 1e-6f);
        unsigned u0 = (unsigned)f2bf(v.x * invn) | ((unsigned)f2bf(v.y * invn) << 16);
        unsigned u1 = (unsigned)f2bf(v.z * invn) | ((unsigned)f2bf(v.w * invn) << 16);
        *reinterpret_cast<uint2*>(fnbf + (size_t)rg0 * D + lane * 4) = make_uint2(u0, u1);

        if (lane < C) {
            float x = logits[(size_t)rg0 * C + lane];
            float mx = x;
#pragma unroll
            for (int off = 16; off; off >>= 1) mx = fmaxf(mx, __shfl_xor(mx, off, 32));
            float e = expf(x - mx);
            const float fc = (float)lane;
            float s0 = e, s1 = e * fc, s2 = e * fc * fc;
#pragma unroll
            for (int off = 16; off; off >>= 1) {
                s0 += __shfl_xor(s0, off, 32);
                s1 += __shfl_xor(s1, off, 32);
                s2 += __shfl_xor(s2, off, 32);
            }
            if (lane == 0) mu0[rg0] = make_float2(s1 / s0, s2 / s0);
        }

        if (lane == 0) {
            const float* rp = rois + (size_t)rg0 * 6;
            float a0 = rp[0], a1 = rp[1], a2 = rp[2], a3 = rp[3], a4 = rp[4], a5 = rp[5];
            float cx = (a0 + a3) * 0.5f, cy = (a1 + a4) * 0.5f, cz = (a2 + a5) * 0.5f;
            float sq = cx * cx + cy * cy + cz * cz;
            float s = fabsf(a0) + fabsf(a1) + fabsf(a2) + fabsf(a3) + fabsf(a4) + fabsf(a5);
            centers4[rg0] = make_float4(cx, cy, cz, (s > 0.0f) ? sq : INFINITY);
        }
    }

    // ---- stage LDS center table directly from rois ----
    {
        const float2* rois2 = reinterpret_cast<const float2*>(rois);
        for (int i = t; i < N; i += 1024) {
            const size_t rb = (size_t)(gbase + i) * 3;
            float2 p0 = rois2[rb], p1 = rois2[rb + 1], p2 = rois2[rb + 2];
            float cx = (p0.x + p1.y) * 0.5f;
            float cy = (p0.y + p2.x) * 0.5f;
            float cz = (p1.x + p2.y) * 0.5f;
            float sq = cx * cx + cy * cy + cz * cz;
            float s = fabsf(p0.x) + fabsf(p0.y) + fabsf(p1.x)
                    + fabsf(p1.y) + fabsf(p2.x) + fabsf(p2.y);
            s_c[i] = make_float4(cx, cy, cz, (s > 0.0f) ? sq : INFINITY);
        }
    }
    __syncthreads();

    // wave-owned candidate chunk, kept in registers
    float4 cmv[4];
    int    mv[4];
#pragma unroll
    for (int u = 0; u < 4; ++u) {
        mv[u] = (wv << 8) + (u << 6) + lane;
        cmv[u] = s_c[mv[u]];
    }

    // ---- pass 1: per-row min over this lane's 4 candidates; merge via atomicMin ----
#pragma unroll 4
    for (int rr = 0; rr < 16; ++rr) {
        const int nrow = nbase + rr;
        const float4 rc = s_c[nrow];       // same-address broadcast, conflict-free
        float mn = INFINITY;
#pragma unroll
        for (int u = 0; u < 4; ++u) {
            float dist = fmaxf(rc.w + cmv[u].w -
                               2.0f * (rc.x * cmv[u].x + rc.y * cmv[u].y + rc.z * cmv[u].z), 0.0f);
            mn = fminf(mn, (mv[u] == nrow) ? INFINITY : dist);
        }
        atomicMin(&s_pm[rr][lane], __float_as_uint(mn));
    }
    __syncthreads();

    // ---- tau per row: wave rr sorts its row's 64 subset minima ----
    {
        float v = __uint_as_float(s_pm[wv][lane]);
#pragma unroll
        for (int k = 2; k <= 64; k <<= 1) {
#pragma unroll
            for (int j = k >> 1; j > 0; j >>= 1) {
                float o = __shfl_xor(v, j);
                bool take_min = (((lane & j) == 0) == ((lane & k) == 0));
                v = take_min ? fminf(v, o) : fmaxf(v, o);
            }
        }
        if (lane == 15) s_tau[wv] = v;     // 16th smallest
    }
    __syncthreads();

    // ---- pass 2: append survivors from the register chunk for all 16 rows ----
#pragma unroll 4
    for (int rr = 0; rr < 16; ++rr) {
        const int nrow = nbase + rr;
        const float tau = s_tau[rr];
        const float4 rc = s_c[nrow];
#pragma unroll
        for (int u = 0; u < 4; ++u) {
            float dist = fmaxf(rc.w + cmv[u].w -
                               2.0f * (rc.x * cmv[u].x + rc.y * cmv[u].y + rc.z * cmv[u].z), 0.0f);
            if (dist <= tau && mv[u] != nrow) {
                int pos = atomicAdd(&s_cnt[rr], 1);
                if (pos < 64)
                    s_buf[rr][pos] = ((unsigned long long)__float_as_uint(dist) << 32)
                                     | (unsigned)mv[u];
            }
        }
    }
    __syncthreads();

    // ---- selection: wave rr owns row rr ----
    const int rg = r0 + wv;                // global row
    const int n = nbase + wv;              // in-batch row
    const int cnt = s_cnt[wv];

    int my_sel = -1;
    if (cnt <= 64) {
        unsigned long long key = (lane < cnt) ? s_buf[wv][lane] : ~0ull;
#pragma unroll
        for (int k = 2; k <= 64; k <<= 1) {
#pragma unroll
            for (int j = k >> 1; j > 0; j >>= 1) {
                unsigned long long o = __shfl_xor(key, j);
                bool take_min = (((lane & j) == 0) == ((lane & k) == 0));
                unsigned long long mn = (key < o) ? key : o;
                unsigned long long mx = (key < o) ? o : key;
                key = take_min ? mn : mx;
            }
        }
        if (lane < K && key != ~0ull) my_sel = (int)(unsigned)key;
    } else {
        // exact fallback: 16 rounds of full rescan-argmin over LDS table
        const float4 cq = s_c[n];
        unsigned long long removed = 0ull;
        for (int round = 0; round < K; ++round) {
            float bd = INFINITY; int bi = 0x7FFFFFFF;
            for (int j = 0; j < 64; ++j) {
                const int m = lane + (j << 6);
                float4 cm = s_c[m];
                float dist = fmaxf(cq.w + cm.w -
                                   2.0f * (cq.x * cm.x + cq.y * cm.y + cq.z * cm.z), 0.0f);
                bool skip = ((removed >> j) & 1ull) || (m == n);
                if (!skip && dist < bd) { bd = dist; bi = m; }
            }
            float md = bd;
#pragma unroll
            for (int off = 32; off; off >>= 1) md = fminf(md, __shfl_xor(md, off));
            if (md == INFINITY) break;
            int kk = (bd == md) ? bi : 0x7FFFFFFF;
#pragma unroll
            for (int off = 32; off; off >>= 1) kk = min(kk, __shfl_xor(kk, off));
            if (lane == round) my_sel = kk;
            if (kk == bi) removed |= 1ull << (bi >> 6);
        }
    }

    if (my_sel >= 0) {
        atomicOr(&adj[(size_t)rg * NW + (my_sel >> 5)], 1u << (my_sel & 31));
        atomicOr(&adj[(size_t)(gbase + my_sel) * NW + (n >> 5)], 1u << (n & 31));
    }
}

// ---------------------------------------------------------------------------
// Kernel 2: build weighted neighbor lists — barrier-free, one wave per row
// (R13 structure; mu0 tail moved to knn).
__global__ __launch_bounds__(256) void build_kernel(const unsigned short* __restrict__ fnbf,
                             const float4* __restrict__ centers4,
                             const unsigned* __restrict__ adj,
                             uint2* __restrict__ nbr,
                             int* __restrict__ nbr_cnt,
                             const float* __restrict__ raw_sigma) {
    const int t = threadIdx.x;
    const int lane = t & 63;
    const int wv = t >> 6;          // 0..3
    const int r = blockIdx.x * 4 + wv;
    const int base = r - (r & (N - 1));

    __shared__ float4 s_q[4][16 * 5];   // per-wave padded Q: idx 5e+s (+1 pad/e)
    __shared__ int    s_list[4][CAP];
    __shared__ float  s_w[4][CAP];

    // ---- adjacency compaction (wave-local, ascending => deterministic) ----
    uint2 wpair = *reinterpret_cast<const uint2*>(adj + (size_t)r * NW + 2 * lane);
    const int pc = __popc(wpair.x) + __popc(wpair.y);
    int sc = pc;
#pragma unroll
    for (int off = 1; off < 64; off <<= 1) {
        int o = __shfl_up(sc, off);
        if (lane >= off) sc += o;
    }
    const int total = __shfl(sc, 63);
    const int cnt = total > CAP ? CAP : total;
    int o = sc - pc;                   // exclusive prefix
    {
        unsigned ww = wpair.x; int mb = lane * 64;
        while (ww) { int b = __ffs(ww) - 1; if (o < CAP) s_list[wv][o] = mb + b; ++o; ww &= ww - 1; }
        ww = wpair.y; mb = lane * 64 + 32;
        while (ww) { int b = __ffs(ww) - 1; if (o < CAP) s_list[wv][o] = mb + b; ++o; ww &= ww - 1; }
    }

    // ---- stage q row (bf16 -> f32) into padded per-wave layout ----
    {
        uint2 qw = *reinterpret_cast<const uint2*>(fnbf + (size_t)r * D + 4 * lane);
        float4 qv = make_float4(bflo(qw.x), bfhi(qw.x), bflo(qw.y), bfhi(qw.y));
        const int e = (lane & 31) >> 1;
        const int s = ((lane >> 5) << 1) | (lane & 1);
        s_q[wv][5 * e + s] = qv;
    }

    const float rs = raw_sigma[0];
    const float sigma = fmaxf(log1pf(expf(rs)), 1e-6f);
    const float nhalf_inv_s2 = -0.5f / (sigma * sigma);
    const float4 cq = centers4[r];
    const uint4* fn4 = reinterpret_cast<const uint4*>(fnbf);

    // ---- gather: 16-lane groups, 4 neighbors per wave per step ----
    {
        const int g = lane >> 4;    // neighbor slot (0..3)
        const int e = lane & 15;    // element slice (0..15)
        for (int i0 = 0; i0 < cnt; i0 += 4) {
            const int i = i0 + g;
            const bool act = (i < cnt);
            const int gm = base + s_list[wv][act ? i : 0];
            uint4 a = fn4[(size_t)gm * 32 + e];        // elems [8e, 8e+8)
            uint4 b = fn4[(size_t)gm * 32 + 16 + e];   // elems [128+8e, 128+8e+8)
            float4 cm = centers4[gm];                  // broadcast within group
            float4 qa0 = s_q[wv][5 * e + 0], qa1 = s_q[wv][5 * e + 1];
            float4 qb0 = s_q[wv][5 * e + 2], qb1 = s_q[wv][5 * e + 3];
            float p = bflo(a.x) * qa0.x + bfhi(a.x) * qa0.y
                    + bflo(a.y) * qa0.z + bfhi(a.y) * qa0.w
                    + bflo(a.z) * qa1.x + bfhi(a.z) * qa1.y
                    + bflo(a.w) * qa1.z + bfhi(a.w) * qa1.w
                    + bflo(b.x) * qb0.x + bfhi(b.x) * qb0.y
                    + bflo(b.y) * qb0.z + bfhi(b.y) * qb0.w
                    + bflo(b.z) * qb1.x + bfhi(b.z) * qb1.y
                    + bflo(b.w) * qb1.z + bfhi(b.w) * qb1.w;
#pragma unroll
            for (int off = 1; off < 16; off <<= 1) p += __shfl_xor(p, off);
            float aff = fminf(fmaxf((p + 1.0f) * 0.5f, 0.0f), 1.0f);
            float dist = fmaxf(cq.w + cm.w -
                               2.0f * (cq.x * cm.x + cq.y * cm.y + cq.z * cm.z), 0.0f);
            if (e == 0 && act) s_w[wv][i] = expf(dist * nhalf_inv_s2) * aff;
        }
    }

    // ---- wave-local weight sum (deterministic) + normalize + write ----
    float ps = 0.0f;
    for (int i = lane; i < cnt; i += 64) ps += s_w[wv][i];
#pragma unroll
    for (int off = 32; off; off >>= 1) ps += __shfl_xor(ps, off);
    const float inv_sum = 1.0f / fmaxf(ps, 1e-6f);

    for (int i = lane; i < cnt; i += 64) {
        nbr[(size_t)r * CAP + i] = make_uint2((unsigned)s_list[wv][i],
                                              __float_as_uint(s_w[wv][i] * inv_sum));
    }
    if (lane == 0) nbr_cnt[r] = cnt;
}

// ---------------------------------------------------------------------------
// Kernel 3: one mean-field iteration, MOMENT-COMPRESSED (R9/R14 structure).
__global__ void iter_kernel(const float* __restrict__ logits,
                            const uint2* __restrict__ nbr,
                            const int* __restrict__ nbr_cnt,
                            const float2* __restrict__ mu_in,
                            float2* __restrict__ mu_out,
                            float* __restrict__ out,
                            const float* __restrict__ raw_smooth,
                            int last) {
    const int t = threadIdx.x;
    const int r = blockIdx.x * 8 + (t >> 5);
    const int c = t & 31;
    const int base = r - (r & (N - 1));
    const float smooth = log1pf(expf(raw_smooth[0]));

    const int cnt = nbr_cnt[r];
    const uint2* np = nbr + (size_t)r * CAP;

    float m0 = 0.0f, m1 = 0.0f, m2 = 0.0f;
    for (int j = c; j < cnt; j += 32) {
        uint2 e = np[j];
        float w = __uint_as_float(e.y);
        float2 mu = mu_in[base + (int)e.x];
        m0 += w; m1 += w * mu.x; m2 += w * mu.y;
    }
#pragma unroll
    for (int off = 16; off; off >>= 1) {
        m0 += __shfl_xor(m0, off, 32);
        m1 += __shfl_xor(m1, off, 32);
        m2 += __shfl_xor(m2, off, 32);
    }

    const float fc = (float)c;
    float pw = (m2 - 2.0f * fc * m1 + fc * fc * m0) * (1.0f / 961.0f);
    float refined = logits[(size_t)r * C + c] - smooth * pw;

    if (last) {
        out[(size_t)r * C + c] = refined;
        return;
    }

    float mx = refined;
#pragma unroll
    for (int off = 16; off; off >>= 1) mx = fmaxf(mx, __shfl_xor(mx, off, 32));
    float e = expf(refined - mx);
    float s0 = e, s1 = e * fc, s2 = e * fc * fc;
#pragma unroll
    for (int off = 16; off; off >>= 1) {
        s0 += __shfl_xor(s0, off, 32);
        s1 += __shfl_xor(s1, off, 32);
        s2 += __shfl_xor(s2, off, 32);
    }
    if (c == 0) mu_out[r] = make_float2(s1 / s0, s2 / s0);
}

// ---------------------------------------------------------------------------
extern "C" void kernel_launch(void* const* d_in, const int* in_sizes, int n_in,
                              void* d_out, int out_size, void* d_ws, size_t ws_size,
                              hipStream_t stream) {
    const float* logits     = (const float*)d_in[0];
    const float* rois       = (const float*)d_in[1];
    const float* feats      = (const float*)d_in[2];
    const float* raw_sigma  = (const float*)d_in[3];
    const float* raw_smooth = (const float*)d_in[4];
    float* out = (float*)d_out;

    char* ws = (char*)d_ws;
    size_t off = 0;
    auto alloc = [&](size_t bytes) -> void* {
        void* p = ws + off;
        off += (bytes + 255) & ~(size_t)255;
        return p;
    };
    float4*         centers4 = (float4*)        alloc((size_t)ROWS * sizeof(float4));
    unsigned short* fnbf     = (unsigned short*)alloc((size_t)ROWS * D * 2);
    unsigned*       adj      = (unsigned*)      alloc((size_t)ROWS * NW * 4);
    uint2*          nbr      = (uint2*)         alloc((size_t)ROWS * CAP * 8);
    int*            nbr_cnt  = (int*)           alloc((size_t)ROWS * 4);
    float2*         mu_a     = (float2*)        alloc((size_t)ROWS * 8);
    float2*         mu_b     = (float2*)        alloc((size_t)ROWS * 8);

    hipMemsetAsync(adj, 0, (size_t)ROWS * NW * 4, stream);
    knn_kernel<<<ROWS / 16, 1024, 0, stream>>>(rois, feats, logits, centers4,
                                               fnbf, mu_a, adj);
    build_kernel<<<ROWS / 4, 256, 0, stream>>>(fnbf, centers4, adj,
                                               nbr, nbr_cnt, raw_sigma);

    float2* mi = mu_a;
    float2* mo = mu_b;
    for (int it = 0; it < 5; ++it) {
        iter_kernel<<<ROWS / 8, 256, 0, stream>>>(logits, nbr, nbr_cnt,
                                                  mi, mo, out, raw_smooth,
                                                  (it == 4) ? 1 : 0);
        float2* tmp = mi; mi = mo; mo = tmp;
    }
}

// Round 21
// 70.905 us; speedup vs baseline: 5.1894x; 1.0509x over previous
//
#include <hip/hip_runtime.h>
#include <math.h>

// Problem constants (match reference setup_inputs)
constexpr int B = 2;
constexpr int N = 4096;
constexpr int C = 32;
constexpr int D = 256;
constexpr int K = 16;
constexpr int NW = N / 32;   // adjacency bitmask words per row = 128
constexpr int CAP = 128;     // max neighbors per row (16 out + in-degree)
constexpr int ROWS = B * N;  // 8192

__device__ __forceinline__ unsigned short f2bf(float f) {   // RNE f32 -> bf16
    unsigned u = __float_as_uint(f);
    return (unsigned short)((u + 0x7fffu + ((u >> 16) & 1u)) >> 16);
}
__device__ __forceinline__ float bflo(unsigned u) { return __uint_as_float(u << 16); }
__device__ __forceinline__ float bfhi(unsigned u) { return __uint_as_float(u & 0xffff0000u); }

// ---------------------------------------------------------------------------
// Kernel 1: per-row preprocess: centers(+sqnorm or INF if invalid), and a
// PRE-NORMALIZED bf16 copy of the feature row. One wave per row; also zeroes
// the adjacency bitmask (no separate memset dispatch).
__global__ void pre_kernel(const float* __restrict__ rois,
                           const float* __restrict__ feats,
                           float4* __restrict__ centers4,
                           unsigned short* __restrict__ fnbf,
                           uint2* __restrict__ adj_zero) {
    const int t = threadIdx.x;
    const int wid = t >> 6, lane = t & 63;
    const int r = blockIdx.x * 4 + wid;

    // zero adjacency: 2048 blocks * 256 threads == ROWS*NW/2 uint2 elements
    adj_zero[blockIdx.x * 256 + t] = make_uint2(0u, 0u);

    if (r >= ROWS) return;

    const float4* f4 = reinterpret_cast<const float4*>(feats) + (size_t)r * (D / 4);
    float4 v = f4[lane];
    float ss = v.x * v.x + v.y * v.y + v.z * v.z + v.w * v.w;
#pragma unroll
    for (int off = 32; off; off >>= 1) ss += __shfl_xor(ss, off);

    const float invn = 1.0f / fmaxf(sqrtf(ss), 1e-6f);
    unsigned u0 = (unsigned)f2bf(v.x * invn) | ((unsigned)f2bf(v.y * invn) << 16);
    unsigned u1 = (unsigned)f2bf(v.z * invn) | ((unsigned)f2bf(v.w * invn) << 16);
    *reinterpret_cast<uint2*>(fnbf + (size_t)r * D + lane * 4) = make_uint2(u0, u1);

    if (lane == 0) {
        const float* rp = rois + (size_t)r * 6;
        float a0 = rp[0], a1 = rp[1], a2 = rp[2], a3 = rp[3], a4 = rp[4], a5 = rp[5];
        float cx = (a0 + a3) * 0.5f, cy = (a1 + a4) * 0.5f, cz = (a2 + a5) * 0.5f;
        float sq = cx * cx + cy * cy + cz * cz;
        float s = fabsf(a0) + fabsf(a1) + fabsf(a2) + fabsf(a3) + fabsf(a4) + fabsf(a5);
        centers4[r] = make_float4(cx, cy, cz, (s > 0.0f) ? sq : INFINITY);
    }
}

// ---------------------------------------------------------------------------
// Kernel 2: exact 16-NN, chunk-in-register structure (R8). 1024 thr = 16
// waves; block covers 16 rows of one batch. Each wave owns a 256-candidate
// chunk in registers and evaluates it against all 16 row centers; subset
// minima merged via LDS atomicMin; tau = 16th-smallest of 64 subset minima;
// survivor collection + u64 bitonic sort => exact lax.top_k-compatible
// top-16 (ties -> smaller index). Overflow/invalid -> exact fallback.
__global__ __launch_bounds__(1024, 8) void knn_kernel(const float4* __restrict__ centers4,
                                                      unsigned* __restrict__ adj) {
    __shared__ float4 s_c[N];                        // 64 KB
    __shared__ unsigned s_pm[16][64];                // 4 KB subset-min bits
    __shared__ unsigned long long s_buf[16][64];     // 8 KB survivor keys
    __shared__ int s_cnt[16];
    __shared__ float s_tau[16];

    const int t = threadIdx.x;
    const int lane = t & 63;
    const int wv = t >> 6;
    const int r0 = blockIdx.x * 16;        // first global row of block
    const int nbase = r0 & (N - 1);        // first in-batch row index
    const int gbase = r0 - nbase;          // batch offset (0 or N)

    if (t < 16) s_cnt[t] = 0;
    ((unsigned*)s_pm)[t] = 0x7F800000u;    // +INF bits (1024 entries exactly)
    for (int i = t; i < N; i += 1024) s_c[i] = centers4[gbase + i];
    __syncthreads();

    // wave-owned candidate chunk, kept in registers
    float4 cmv[4];
    int    mv[4];
#pragma unroll
    for (int u = 0; u < 4; ++u) {
        mv[u] = (wv << 8) + (u << 6) + lane;
        cmv[u] = s_c[mv[u]];
    }

    // ---- pass 1: per-row min over this lane's 4 candidates; merge via atomicMin ----
#pragma unroll 4
    for (int rr = 0; rr < 16; ++rr) {
        const int nrow = nbase + rr;
        const float4 rc = s_c[nrow];       // same-address broadcast, conflict-free
        float mn = INFINITY;
#pragma unroll
        for (int u = 0; u < 4; ++u) {
            float dist = fmaxf(rc.w + cmv[u].w -
                               2.0f * (rc.x * cmv[u].x + rc.y * cmv[u].y + rc.z * cmv[u].z), 0.0f);
            mn = fminf(mn, (mv[u] == nrow) ? INFINITY : dist);
        }
        atomicMin(&s_pm[rr][lane], __float_as_uint(mn));
    }
    __syncthreads();

    // ---- tau per row: wave rr sorts its row's 64 subset minima ----
    {
        float v = __uint_as_float(s_pm[wv][lane]);
#pragma unroll
        for (int k = 2; k <= 64; k <<= 1) {
#pragma unroll
            for (int j = k >> 1; j > 0; j >>= 1) {
                float o = __shfl_xor(v, j);
                bool take_min = (((lane & j) == 0) == ((lane & k) == 0));
                v = take_min ? fminf(v, o) : fmaxf(v, o);
            }
        }
        if (lane == 15) s_tau[wv] = v;     // 16th smallest
    }
    __syncthreads();

    // ---- pass 2: append survivors from the register chunk for all 16 rows ----
#pragma unroll 4
    for (int rr = 0; rr < 16; ++rr) {
        const int nrow = nbase + rr;
        const float tau = s_tau[rr];
        const float4 rc = s_c[nrow];
#pragma unroll
        for (int u = 0; u < 4; ++u) {
            float dist = fmaxf(rc.w + cmv[u].w -
                               2.0f * (rc.x * cmv[u].x + rc.y * cmv[u].y + rc.z * cmv[u].z), 0.0f);
            if (dist <= tau && mv[u] != nrow) {
                int pos = atomicAdd(&s_cnt[rr], 1);
                if (pos < 64)
                    s_buf[rr][pos] = ((unsigned long long)__float_as_uint(dist) << 32)
                                     | (unsigned)mv[u];
            }
        }
    }
    __syncthreads();

    // ---- selection: wave rr owns row rr ----
    const int rg = r0 + wv;                // global row
    const int n = nbase + wv;              // in-batch row
    const int cnt = s_cnt[wv];

    int my_sel = -1;
    if (cnt <= 64) {
        unsigned long long key = (lane < cnt) ? s_buf[wv][lane] : ~0ull;
#pragma unroll
        for (int k = 2; k <= 64; k <<= 1) {
#pragma unroll
            for (int j = k >> 1; j > 0; j >>= 1) {
                unsigned long long o = __shfl_xor(key, j);
                bool take_min = (((lane & j) == 0) == ((lane & k) == 0));
                unsigned long long mn = (key < o) ? key : o;
                unsigned long long mx = (key < o) ? o : key;
                key = take_min ? mn : mx;
            }
        }
        if (lane < K && key != ~0ull) my_sel = (int)(unsigned)key;
    } else {
        // exact fallback: 16 rounds of full rescan-argmin over LDS table
        const float4 cq = s_c[n];
        unsigned long long removed = 0ull;
        for (int round = 0; round < K; ++round) {
            float bd = INFINITY; int bi = 0x7FFFFFFF;
            for (int j = 0; j < 64; ++j) {
                const int m = lane + (j << 6);
                float4 cm = s_c[m];
                float dist = fmaxf(cq.w + cm.w -
                                   2.0f * (cq.x * cm.x + cq.y * cm.y + cq.z * cm.z), 0.0f);
                bool skip = ((removed >> j) & 1ull) || (m == n);
                if (!skip && dist < bd) { bd = dist; bi = m; }
            }
            float md = bd;
#pragma unroll
            for (int off = 32; off; off >>= 1) md = fminf(md, __shfl_xor(md, off));
            if (md == INFINITY) break;
            int kk = (bd == md) ? bi : 0x7FFFFFFF;
#pragma unroll
            for (int off = 32; off; off >>= 1) kk = min(kk, __shfl_xor(kk, off));
            if (lane == round) my_sel = kk;
            if (kk == bi) removed |= 1ull << (bi >> 6);
        }
    }

    if (my_sel >= 0) {
        atomicOr(&adj[(size_t)rg * NW + (my_sel >> 5)], 1u << (my_sel & 31));
        atomicOr(&adj[(size_t)(gbase + my_sel) * NW + (n >> 5)], 1u << (n & 31));
    }
}

// ---------------------------------------------------------------------------
// Kernel 3: build weighted neighbor lists — BARRIER-FREE, ONE WAVE PER ROW
// (4 independent waves per 256-thread block, zero __syncthreads).
// Per wave: uint2 adjacency read (lane l owns m in [64l,64l+64) -> ascending
// deterministic compaction), wave shfl_up prefix, q row staged to a 5-stride
// padded per-wave LDS area (2-way banks = free), then the 16-lane-group
// bf16 cosine gather (4 neighbors concurrently), wave-local sum/normalize,
// and the fused softmax-moments mu0 on lanes 0..31.
__global__ __launch_bounds__(256) void build_kernel(const unsigned short* __restrict__ fnbf,
                             const float4* __restrict__ centers4,
                             const unsigned* __restrict__ adj,
                             uint2* __restrict__ nbr,
                             int* __restrict__ nbr_cnt,
                             const float* __restrict__ raw_sigma,
                             const float* __restrict__ logits,
                             float2* __restrict__ mu0) {
    const int t = threadIdx.x;
    const int lane = t & 63;
    const int wv = t >> 6;          // 0..3
    const int r = blockIdx.x * 4 + wv;
    const int base = r - (r & (N - 1));

    __shared__ float4 s_q[4][16 * 5];   // per-wave padded Q: idx 5e+s (+1 pad/e)
    __shared__ int    s_list[4][CAP];
    __shared__ float  s_w[4][CAP];

    // ---- adjacency compaction (wave-local, ascending => deterministic) ----
    uint2 wpair = *reinterpret_cast<const uint2*>(adj + (size_t)r * NW + 2 * lane);
    const int pc = __popc(wpair.x) + __popc(wpair.y);
    int sc = pc;
#pragma unroll
    for (int off = 1; off < 64; off <<= 1) {
        int o = __shfl_up(sc, off);
        if (lane >= off) sc += o;
    }
    const int total = __shfl(sc, 63);
    const int cnt = total > CAP ? CAP : total;
    int o = sc - pc;                   // exclusive prefix
    {
        unsigned ww = wpair.x; int mb = lane * 64;
        while (ww) { int b = __ffs(ww) - 1; if (o < CAP) s_list[wv][o] = mb + b; ++o; ww &= ww - 1; }
        ww = wpair.y; mb = lane * 64 + 32;
        while (ww) { int b = __ffs(ww) - 1; if (o < CAP) s_list[wv][o] = mb + b; ++o; ww &= ww - 1; }
    }

    // ---- stage q row (bf16 -> f32) into padded per-wave layout ----
    {
        uint2 qw = *reinterpret_cast<const uint2*>(fnbf + (size_t)r * D + 4 * lane);
        float4 qv = make_float4(bflo(qw.x), bfhi(qw.x), bflo(qw.y), bfhi(qw.y));
        const int e = (lane & 31) >> 1;
        const int s = ((lane >> 5) << 1) | (lane & 1);
        s_q[wv][5 * e + s] = qv;       // elems: s0=[8e,8e+4) s1=[8e+4,8e+8) s2=[128+8e..) s3=...
    }

    const float rs = raw_sigma[0];
    const float sigma = fmaxf(log1pf(expf(rs)), 1e-6f);
    const float nhalf_inv_s2 = -0.5f / (sigma * sigma);
    const float4 cq = centers4[r];
    const uint4* fn4 = reinterpret_cast<const uint4*>(fnbf);

    // ---- gather: 16-lane groups, 4 neighbors per wave per step ----
    {
        const int g = lane >> 4;    // neighbor slot (0..3)
        const int e = lane & 15;    // element slice (0..15)
        for (int i0 = 0; i0 < cnt; i0 += 4) {
            const int i = i0 + g;
            const bool act = (i < cnt);
            const int gm = base + s_list[wv][act ? i : 0];
            uint4 a = fn4[(size_t)gm * 32 + e];        // elems [8e, 8e+8)
            uint4 b = fn4[(size_t)gm * 32 + 16 + e];   // elems [128+8e, 128+8e+8)
            float4 cm = centers4[gm];                  // broadcast within group
            float4 qa0 = s_q[wv][5 * e + 0], qa1 = s_q[wv][5 * e + 1];
            float4 qb0 = s_q[wv][5 * e + 2], qb1 = s_q[wv][5 * e + 3];
            float p = bflo(a.x) * qa0.x + bfhi(a.x) * qa0.y
                    + bflo(a.y) * qa0.z + bfhi(a.y) * qa0.w
                    + bflo(a.z) * qa1.x + bfhi(a.z) * qa1.y
                    + bflo(a.w) * qa1.z + bfhi(a.w) * qa1.w
                    + bflo(b.x) * qb0.x + bfhi(b.x) * qb0.y
                    + bflo(b.y) * qb0.z + bfhi(b.y) * qb0.w
                    + bflo(b.z) * qb1.x + bfhi(b.z) * qb1.y
                    + bflo(b.w) * qb1.z + bfhi(b.w) * qb1.w;
#pragma unroll
            for (int off = 1; off < 16; off <<= 1) p += __shfl_xor(p, off);
            float aff = fminf(fmaxf((p + 1.0f) * 0.5f, 0.0f), 1.0f);
            float dist = fmaxf(cq.w + cm.w -
                               2.0f * (cq.x * cm.x + cq.y * cm.y + cq.z * cm.z), 0.0f);
            if (e == 0 && act) s_w[wv][i] = expf(dist * nhalf_inv_s2) * aff;
        }
    }

    // ---- wave-local weight sum (deterministic) + normalize + write ----
    float ps = 0.0f;
    for (int i = lane; i < cnt; i += 64) ps += s_w[wv][i];
#pragma unroll
    for (int off = 32; off; off >>= 1) ps += __shfl_xor(ps, off);
    const float inv_sum = 1.0f / fmaxf(ps, 1e-6f);

    for (int i = lane; i < cnt; i += 64) {
        nbr[(size_t)r * CAP + i] = make_uint2((unsigned)s_list[wv][i],
                                              __float_as_uint(s_w[wv][i] * inv_sum));
    }
    if (lane == 0) nbr_cnt[r] = cnt;

    // ---- fused initial softmax moments (lanes 0..31) ----
    if (lane < C) {
        float x = logits[(size_t)r * C + lane];
        float mx = x;
#pragma unroll
        for (int off = 16; off; off >>= 1) mx = fmaxf(mx, __shfl_xor(mx, off, 32));
        float e = expf(x - mx);
        const float fc = (float)lane;
        float s0 = e, s1 = e * fc, s2 = e * fc * fc;
#pragma unroll
        for (int off = 16; off; off >>= 1) {
            s0 += __shfl_xor(s0, off, 32);
            s1 += __shfl_xor(s1, off, 32);
            s2 += __shfl_xor(s2, off, 32);
        }
        if (lane == 0) mu0[r] = make_float2(s1 / s0, s2 / s0);
    }
}

// ---------------------------------------------------------------------------
// Kernel 4: one mean-field iteration, MOMENT-COMPRESSED. Per row only
// (mu1, mu2) float2 is gathered per neighbor; m0 accumulates the stored
// weights. refined = logits - smooth*(m2 - 2c*m1 + c^2*m0)/961; softmax in
// registers; only the new mu float2 is written (q never hits memory).
__global__ void iter_kernel(const float* __restrict__ logits,
                            const uint2* __restrict__ nbr,
                            const int* __restrict__ nbr_cnt,
                            const float2* __restrict__ mu_in,
                            float2* __restrict__ mu_out,
                            float* __restrict__ out,
                            const float* __restrict__ raw_smooth,
                            int last) {
    const int t = threadIdx.x;
    const int r = blockIdx.x * 8 + (t >> 5);
    const int c = t & 31;
    const int base = r - (r & (N - 1));
    const float smooth = log1pf(expf(raw_smooth[0]));

    const int cnt = nbr_cnt[r];
    const uint2* np = nbr + (size_t)r * CAP;

    float m0 = 0.0f, m1 = 0.0f, m2 = 0.0f;
    for (int j = c; j < cnt; j += 32) {
        uint2 e = np[j];
        float w = __uint_as_float(e.y);
        float2 mu = mu_in[base + (int)e.x];
        m0 += w; m1 += w * mu.x; m2 += w * mu.y;
    }
#pragma unroll
    for (int off = 16; off; off >>= 1) {
        m0 += __shfl_xor(m0, off, 32);
        m1 += __shfl_xor(m1, off, 32);
        m2 += __shfl_xor(m2, off, 32);
    }

    const float fc = (float)c;
    float pw = (m2 - 2.0f * fc * m1 + fc * fc * m0) * (1.0f / 961.0f);
    float refined = logits[(size_t)r * C + c] - smooth * pw;

    if (last) {
        out[(size_t)r * C + c] = refined;
        return;
    }

    float mx = refined;
#pragma unroll
    for (int off = 16; off; off >>= 1) mx = fmaxf(mx, __shfl_xor(mx, off, 32));
    float e = expf(refined - mx);
    float s0 = e, s1 = e * fc, s2 = e * fc * fc;
#pragma unroll
    for (int off = 16; off; off >>= 1) {
        s0 += __shfl_xor(s0, off, 32);
        s1 += __shfl_xor(s1, off, 32);
        s2 += __shfl_xor(s2, off, 32);
    }
    if (c == 0) mu_out[r] = make_float2(s1 / s0, s2 / s0);
}

// ---------------------------------------------------------------------------
extern "C" void kernel_launch(void* const* d_in, const int* in_sizes, int n_in,
                              void* d_out, int out_size, void* d_ws, size_t ws_size,
                              hipStream_t stream) {
    const float* logits     = (const float*)d_in[0];
    const float* rois       = (const float*)d_in[1];
    const float* feats      = (const float*)d_in[2];
    const float* raw_sigma  = (const float*)d_in[3];
    const float* raw_smooth = (const float*)d_in[4];
    float* out = (float*)d_out;

    char* ws = (char*)d_ws;
    size_t off = 0;
    auto alloc = [&](size_t bytes) -> void* {
        void* p = ws + off;
        off += (bytes + 255) & ~(size_t)255;
        return p;
    };
    float4*         centers4 = (float4*)        alloc((size_t)ROWS * sizeof(float4));
    unsigned short* fnbf     = (unsigned short*)alloc((size_t)ROWS * D * 2);
    unsigned*       adj      = (unsigned*)      alloc((size_t)ROWS * NW * 4);
    uint2*          nbr      = (uint2*)         alloc((size_t)ROWS * CAP * 8);
    int*            nbr_cnt  = (int*)           alloc((size_t)ROWS * 4);
    float2*         mu_a     = (float2*)        alloc((size_t)ROWS * 8);
    float2*         mu_b     = (float2*)        alloc((size_t)ROWS * 8);

    pre_kernel<<<ROWS / 4, 256, 0, stream>>>(rois, feats, centers4, fnbf, (uint2*)adj);
    knn_kernel<<<ROWS / 16, 1024, 0, stream>>>(centers4, adj);
    build_kernel<<<ROWS / 4, 256, 0, stream>>>(fnbf, centers4, adj,
                                               nbr, nbr_cnt, raw_sigma, logits, mu_a);

    float2* mi = mu_a;
    float2* mo = mu_b;
    for (int it = 0; it < 5; ++it) {
        iter_kernel<<<ROWS / 8, 256, 0, stream>>>(logits, nbr, nbr_cnt,
                                                  mi, mo, out, raw_smooth,
                                                  (it == 4) ? 1 : 0);
        float2* tmp = mi; mi = mo; mo = tmp;
    }
}